// Round 6
// baseline (202.895 us; speedup 1.0000x reference)
//
#include <hip/hip_runtime.h>
#include <hip/hip_bf16.h>

typedef __attribute__((ext_vector_type(8))) short short8;
typedef __attribute__((ext_vector_type(16))) float f32x16;

#define B_   16
#define O_   512
#define C_   512
#define T_   4096
#define TP   (T_ + 32)     // padded t extent: 16 zero rows each side
#define KT   5
#define BM   128
#define BN   512
#define BK   32
#define NCHUNK (C_/BK)
#define BGR  33            // B row-groups: 33 x 16 rows x 64B

__device__ __forceinline__ void gload_lds16(const void* g, void* l) {
    __builtin_amdgcn_global_load_lds(
        (const __attribute__((address_space(1))) unsigned int*)g,
        (__attribute__((address_space(3))) unsigned int*)l, 16, 0, 0);
}

// ---------------- fused prep: wrepack (blocks 0..5119) + padzero (5120..6143) ----
__global__ void prep_kernel(const float* __restrict__ w,
                            unsigned short* __restrict__ wb,
                            unsigned short* __restrict__ xt) {
    int bid = blockIdx.x;
    if (bid < 5120) {
        int e   = bid * 256 + threadIdx.x;       // e < 5*512*512 exactly
        int n   = e / (O_ * C_);
        int rem = e % (O_ * C_);
        int o   = rem / C_;
        int c   = rem % C_;
        float v = w[((size_t)o * C_ + c) * KT + n];
        __hip_bfloat16 h = __float2bfloat16(v);
        wb[e] = *reinterpret_cast<unsigned short*>(&h);
    } else {
        int i = (bid - 5120) * 256 + threadIdx.x;  // i < 16*32*512 exactly
        int b = i / (32 * C_);
        int r = (i / C_) % 32;
        int c = i % C_;
        int tp = (r < 16) ? r : (T_ + r);          // [0,16) and [T_+16, T_+32)
        xt[((size_t)b * TP + tp) * C_ + c] = 0;
    }
}

// ---------------- x transpose: x[b][c][t] f32 -> xT[b][16+t][c] bf16 ----------------
__global__ void xtrans_kernel(const float* __restrict__ x, unsigned short* __restrict__ xt) {
    __shared__ float tile[64][65];
    int b  = blockIdx.z;
    int c0 = blockIdx.y * 64;
    int t0 = blockIdx.x * 64;
    const float* xb = x + ((size_t)b * C_ + c0) * T_ + t0;
#pragma unroll
    for (int p = 0; p < 4; ++p) {
        int idx = p * 256 + threadIdx.x;
        int cl = idx >> 4;
        int tj = (idx & 15) << 2;
        float4 v = *reinterpret_cast<const float4*>(xb + (size_t)cl * T_ + tj);
        tile[cl][tj + 0] = v.x;
        tile[cl][tj + 1] = v.y;
        tile[cl][tj + 2] = v.z;
        tile[cl][tj + 3] = v.w;
    }
    __syncthreads();
    unsigned short* xtb = xt + ((size_t)b * TP + 16 + t0) * C_ + c0;
#pragma unroll
    for (int p = 0; p < 2; ++p) {
        int g  = p * 256 + threadIdx.x;
        int tl = g >> 3;
        int cj = (g & 7) << 3;
        unsigned short tmp[8];
#pragma unroll
        for (int i = 0; i < 8; ++i) {
            __hip_bfloat16 h = __float2bfloat16(tile[cj + i][tl]);
            tmp[i] = *reinterpret_cast<unsigned short*>(&h);
        }
        *reinterpret_cast<short8*>(xtb + (size_t)tl * C_ + cj) =
            *reinterpret_cast<const short8*>(tmp);
    }
}

// ---------------- conv-as-GEMM, phased pipeline, 32x32x16 MFMA ----------------
// Block tile 128(o) x 512(t), BK=32, 8 waves, wave tile 128x64 (4m x 2n of 32x32).
// A: fragment-major LDS (lane-linear, zero-conflict), frag = 32 rows x 16 k.
// B: row-major [528][32] with slot swizzle q ^= ((row>>1)^(row>>3))&3.
// Per chunk: 5 tap-phases {12 ds_read; <=2 gload_lds prefetch; barrier;
// lgkmcnt(0)+sched_barrier; setprio; 16 MFMA}. vmcnt(0) once per chunk.
__global__ __launch_bounds__(512, 2) void conv_gemm_kernel(
        const unsigned short* __restrict__ wb,
        const unsigned short* __restrict__ xt,
        const float* __restrict__ bias,
        float* __restrict__ out) {
    __shared__ unsigned short a_lds[2][40 * 512];    // 2 x 40960 B
    __shared__ unsigned short b_lds[2][BGR * 512];   // 2 x 33792 B

    // XCD-aware bijective swizzle (512 blocks): o-tile innermost.
    int bid  = blockIdx.x;
    int swzb = (bid & 7) * 64 + (bid >> 3);
    int o0   = (swzb & 3) * BM;
    int t0   = ((swzb >> 2) & 7) * BN;
    int b    = swzb >> 5;

    int tid  = threadIdx.x;
    int lane = tid & 63;
    int wid  = tid >> 6;       // 0..7 = wave n-position
    int l31  = lane & 31;
    int lh   = lane >> 5;      // 0..1

    // chunk-invariant B read offsets (ushort units)
    int bo[KT][2][2];
#pragma unroll
    for (int n = 0; n < KT; ++n)
#pragma unroll
        for (int ni = 0; ni < 2; ++ni)
#pragma unroll
            for (int ks = 0; ks < 2; ++ks) {
                int row = wid * 64 + ni * 32 + l31 + 4 - n;
                int sw  = ((row >> 1) ^ (row >> 3)) & 3;
                bo[n][ni][ks] = row * 32 + ((((ks << 1) + lh) ^ sw) << 3);
            }

    f32x16 acc[4][2];
#pragma unroll
    for (int mi = 0; mi < 4; ++mi)
#pragma unroll
        for (int ni = 0; ni < 2; ++ni)
            acc[mi][ni] = (f32x16)0.0f;

    // per-lane global staging bases
    const unsigned short* ag = wb + (size_t)(o0 + l31) * C_ + lh * 8;
    int c8 = (lane & 3) ^ ((lane >> 3) & 3) ^ ((2 * (wid & 1) + lh) & 3);
    const unsigned short* bg = xt + ((size_t)b * TP + (t0 + 14 + (lane >> 2))) * C_ + c8 * 8;

    int wmi = wid >> 1;        // A-stage: frag m-tile
    int wks = wid & 1;         // A-stage: frag k-slice

    // ---- prologue: stage chunk 0 into buffer 0
#pragma unroll
    for (int k = 0; k < KT; ++k)
        gload_lds16(ag + (size_t)(k * O_ + wmi * 32) * C_ + wks * 16,
                    &a_lds[0][(k * 8 + wid) * 512]);
#pragma unroll
    for (int k = 0; k < 5; ++k) {
        int j = wid + 8 * k;
        if (j < BGR)
            gload_lds16(bg + (size_t)(j * 16) * C_, &b_lds[0][j * 512]);
    }
    asm volatile("s_waitcnt vmcnt(0)" ::: "memory");
    __builtin_amdgcn_s_barrier();

    for (int chunk = 0; chunk < NCHUNK; ++chunk) {
        int cur = chunk & 1;
        const unsigned short* al = a_lds[cur];
        const unsigned short* bl = b_lds[cur];
        int  c1 = (chunk + 1) * BK;
        bool pf = (chunk + 1 < NCHUNK);

#pragma unroll
        for (int n = 0; n < KT; ++n) {
            // ---- phase n: read tap n's fragments
            short8 af[4][2], bf[2][2];
#pragma unroll
            for (int mi = 0; mi < 4; ++mi)
#pragma unroll
                for (int ks = 0; ks < 2; ++ks)
                    af[mi][ks] = *reinterpret_cast<const short8*>(
                        &al[(n * 8 + mi * 2 + ks) * 512 + lane * 8]);
#pragma unroll
            for (int ni = 0; ni < 2; ++ni)
#pragma unroll
                for (int ks = 0; ks < 2; ++ks)
                    bf[ni][ks] = *reinterpret_cast<const short8*>(&bl[bo[n][ni][ks]]);

            // ---- prefetch slice for chunk+1
            if (pf) {
                gload_lds16(ag + (size_t)(n * O_ + wmi * 32) * C_ + wks * 16 + c1,
                            &a_lds[cur ^ 1][(n * 8 + wid) * 512]);
                int j = n * 8 + wid;
                if (j < BGR)
                    gload_lds16(bg + (size_t)(j * 16) * C_ + c1, &b_lds[cur ^ 1][j * 512]);
            }

            __builtin_amdgcn_s_barrier();
            asm volatile("s_waitcnt lgkmcnt(0)" ::: "memory");
            __builtin_amdgcn_sched_barrier(0);

            __builtin_amdgcn_s_setprio(1);
#pragma unroll
            for (int mi = 0; mi < 4; ++mi)
#pragma unroll
                for (int ni = 0; ni < 2; ++ni)
#pragma unroll
                    for (int ks = 0; ks < 2; ++ks)
                        acc[mi][ni] = __builtin_amdgcn_mfma_f32_32x32x16_bf16(
                            af[mi][ks], bf[ni][ks], acc[mi][ni], 0, 0, 0);
            __builtin_amdgcn_s_setprio(0);
        }

        // ---- chunk boundary: next buffer fully staged on all waves
        asm volatile("s_waitcnt vmcnt(0)" ::: "memory");
        __builtin_amdgcn_s_barrier();
    }

    // ---- epilogue: 32x32 C/D layout col=lane&31, row=(reg&3)+8*(reg>>2)+4*(lane>>5)
#pragma unroll
    for (int mi = 0; mi < 4; ++mi) {
#pragma unroll
        for (int ni = 0; ni < 2; ++ni) {
            int tcol = t0 + wid * 64 + ni * 32 + l31;
#pragma unroll
            for (int r = 0; r < 16; ++r) {
                int orow = o0 + mi * 32 + (r & 3) + 8 * (r >> 2) + 4 * lh;
                out[((size_t)b * O_ + orow) * T_ + tcol] =
                    acc[mi][ni][r] + bias[orow];
            }
        }
    }
}

extern "C" void kernel_launch(void* const* d_in, const int* in_sizes, int n_in,
                              void* d_out, int out_size, void* d_ws, size_t ws_size,
                              hipStream_t stream) {
    const float* x    = (const float*)d_in[0];
    const float* w    = (const float*)d_in[1];
    const float* bias = (const float*)d_in[2];
    float* out        = (float*)d_out;

    unsigned short* wb  = (unsigned short*)d_ws;            // 2.62 MB
    unsigned short* xtp = wb + (size_t)KT * O_ * C_;        // 16*4128*512 bf16 = 67.7 MB

    prep_kernel<<<6144, 256, 0, stream>>>(w, wb, xtp);
    xtrans_kernel<<<dim3(T_ / 64, C_ / 64, B_), 256, 0, stream>>>(x, xtp);
    conv_gemm_kernel<<<512, 512, 0, stream>>>(wb, xtp, bias, out);
}